// Round 1
// 625.718 us; speedup vs baseline: 1.2463x; 1.2463x over previous
//
#include <hip/hip_runtime.h>

namespace {

typedef __attribute__((ext_vector_type(8))) short short8;   // 8 bf16 (4 VGPRs)
typedef __attribute__((ext_vector_type(4))) float f32x4;

constexpr int T_LEN = 512;
constexpr int TC    = 16;    // timesteps per x-staging chunk
constexpr int HSTR  = 40;    // h-plane row stride (shorts): 32 used + 8 pad, 80B (16B-mult)
constexpr int XSTR  = 264;   // x-plane row stride (shorts): 256 used + 8 pad, 528B (16B-mult)

__device__ __forceinline__ float fsig(float x) {
    return __builtin_amdgcn_rcpf(1.0f + __expf(-x));
}
__device__ __forceinline__ float ftanh(float x) {
    return 2.0f * __builtin_amdgcn_rcpf(1.0f + __expf(-2.0f * x)) - 1.0f;
}
__device__ __forceinline__ f32x4 mfma16(short8 a, short8 b, f32x4 c) {
    return __builtin_amdgcn_mfma_f32_16x16x32_bf16(a, b, c, 0, 0, 0);
}
// pack bf16-truncations of (a,b) into one dword, b in LOW short
__device__ __forceinline__ unsigned permhi(float a, float b) {
    return __builtin_amdgcn_perm(__float_as_uint(a), __float_as_uint(b), 0x07060302u);
}
__device__ __forceinline__ float lo_resid(float v) {
    return v - __uint_as_float(__float_as_uint(v) & 0xffff0000u);
}
__device__ __forceinline__ short hi16(float v) {
    return (short)(__float_as_uint(v) >> 16);
}

// block = 256 threads = 4 waves over the SAME 16 batch rows.
// waves 0,1 = layer-1 stage (step t), waves 2,3 = layer-2 stage (step t-1) + MLP head.
// Within a layer pair, wave p owns unit-parity p: chunks {gate*2+p}, so each wave has
// a complete (i,f,g,o) gate set for its 16 units -> elementwise halves per wave,
// MFMA count halves per wave (24 vs 48). Bit-identical math to the 2-wave version.
// h1 and h2 handed via 2-slot LDS rings of bf16 hi/lo planes; one barrier per step.
__global__ __launch_bounds__(256)
void lstm2_pipe4_kernel(const float* __restrict__ x,
                        const float* __restrict__ Wih0, const float* __restrict__ Whh0,
                        const float* __restrict__ bih0, const float* __restrict__ bhh0,
                        const float* __restrict__ Wih1, const float* __restrict__ Whh1,
                        const float* __restrict__ bih1, const float* __restrict__ bhh1,
                        const float* __restrict__ W1, const float* __restrict__ b1,
                        const float* __restrict__ W2, const float* __restrict__ b2,
                        float* __restrict__ out)
{
    __shared__ __align__(16) short sh1hi[2][16 * HSTR], sh1lo[2][16 * HSTR]; // h1 ring
    __shared__ __align__(16) short sh2hi[2][16 * HSTR], sh2lo[2][16 * HSTR]; // h2 ring
    __shared__ __align__(16) short sxhi[16 * XSTR],     sxlo[16 * XSTR];     // x chunk
    __shared__ __align__(16) unsigned szero[8];                              // zero pad

    const int tid  = threadIdx.x;
    const int wid  = tid >> 6;           // 0,1 = layer1 pair; 2,3 = layer2 pair
    const int lane = tid & 63;
    const int q    = lane >> 4;          // quad
    const int n    = lane & 15;          // MFMA col (B) / batch row (A)
    const bool isL1 = (wid < 2);
    const int p    = wid & 1;            // unit parity owned by this wave

    // ---- zero h planes ----
    for (int i = tid; i < 16 * HSTR; i += 256) {
        sh1hi[0][i] = 0; sh1hi[1][i] = 0; sh1lo[0][i] = 0; sh1lo[1][i] = 0;
        sh2hi[0][i] = 0; sh2hi[1][i] = 0; sh2lo[0][i] = 0; sh2lo[1][i] = 0;
    }
    if (tid < 8) szero[tid] = 0u;

    // ---- per-wave persistent weight B-fragments + bias C-operands ----
    // this wave's chunk for gate g is old chunk index g*2+p; lane-col n <-> unit (2n+p).
    // L1 K-map: k 0..31 = h1_{t-1}, 32..47 = x_t, 48..63 = 0
    // L2 K-map: k 0..31 = h1_t,     32..63 = h2_{t-1}
    short8 bh[4][2], bl[4][2];
    f32x4  bsp[4];
    #pragma unroll
    for (int gate = 0; gate < 4; ++gate) {
        const int row = gate * 32 + 2 * n + p;
        #pragma unroll
        for (int f = 0; f < 2; ++f) {
            #pragma unroll
            for (int e = 0; e < 8; ++e) {
                const int kk = f * 32 + q * 8 + e;
                float v;
                if (isL1) v = (kk < 32) ? Whh0[row * 32 + kk]
                            : (kk < 48) ? Wih0[row * 16 + (kk - 32)] : 0.0f;
                else      v = (kk < 32) ? Wih1[row * 32 + kk]
                                        : Whh1[row * 32 + (kk - 32)];
                const unsigned b = __float_as_uint(v);
                bh[gate][f][e] = (short)(b >> 16);
                const float hif = __uint_as_float(b & 0xffff0000u);
                bl[gate][f][e] = (short)(__float_as_uint(v - hif) >> 16);
            }
        }
        const float bv = isL1 ? (bih0[row] + bhh0[row]) : (bih1[row] + bhh1[row]);
        bsp[gate] = (f32x4){bv, bv, bv, bv};
    }

    float cst[4];                        // c-state for this wave's parity-p units
    #pragma unroll
    for (int r = 0; r < 4; ++r) cst[r] = 0.f;

    const float4* xg = (const float4*)x + (size_t)blockIdx.x * 16 * (T_LEN * 4);

    #pragma unroll 1
    for (int i = 0; i <= T_LEN; ++i) {
        if (i < T_LEN && (i & (TC - 1)) == 0) {
            __syncthreads();            // prior chunk's reads (iter i-1) are done
            // stage x[t0 = i .. i+15] into hi/lo planes (all 4 waves help)
            const int b = tid & 15, w = tid >> 4;     // batch row, 16 threads/row
            const float4* src = xg + (size_t)b * (T_LEN * 4) + (size_t)i * 4;
            short* dh = &sxhi[b * XSTR];
            short* dl = &sxlo[b * XSTR];
            #pragma unroll
            for (int ii = 0; ii < 4; ++ii) {
                const int el = w + ii * 16;           // float4 index within chunk row
                const float4 v = src[el];
                uint2 hp, lp;
                hp.x = permhi(v.y, v.x);
                hp.y = permhi(v.w, v.z);
                lp.x = permhi(lo_resid(v.y), lo_resid(v.x));
                lp.y = permhi(lo_resid(v.w), lo_resid(v.z));
                *(uint2*)&dh[el * 4] = hp;
                *(uint2*)&dl[el * 4] = lp;
            }
        }
        __syncthreads();

        const bool active = isL1 ? (i < T_LEN) : (i >= 1);
        if (active) {
            const int t = isL1 ? i : (i - 1);
            const short *pa0h, *pa0l, *pa1h, *pa1l;
            short *dhi, *dlo;
            if (isL1) {
                const int ps = (t + 1) & 1;           // slot holding h1_{t-1}
                const int cs = t & 1;                 // slot receiving h1_t
                const int tt = t & (TC - 1);
                pa0h = &sh1hi[ps][n * HSTR + q * 8];
                pa0l = &sh1lo[ps][n * HSTR + q * 8];
                pa1h = (q < 2) ? &sxhi[n * XSTR + tt * 16 + q * 8] : (const short*)szero;
                pa1l = (q < 2) ? &sxlo[n * XSTR + tt * 16 + q * 8] : (const short*)szero;
                dhi = sh1hi[cs]; dlo = sh1lo[cs];
            } else {
                const int s1  = t & 1;                // slot holding h1_t
                const int ps2 = (t + 1) & 1;          // slot holding h2_{t-1}
                pa0h = &sh1hi[s1][n * HSTR + q * 8];
                pa0l = &sh1lo[s1][n * HSTR + q * 8];
                pa1h = &sh2hi[ps2][n * HSTR + q * 8];
                pa1l = &sh2lo[ps2][n * HSTR + q * 8];
                dhi = sh2hi[t & 1]; dlo = sh2lo[t & 1];
            }
            const short8 a0h = *(const short8*)pa0h;
            const short8 a0l = *(const short8*)pa0l;
            const short8 a1h = *(const short8*)pa1h;
            const short8 a1l = *(const short8*)pa1l;

            f32x4 g[4];
            #pragma unroll
            for (int gate = 0; gate < 4; ++gate) {
                f32x4 acc = mfma16(a0h, bh[gate][0], bsp[gate]);
                acc = mfma16(a1h, bh[gate][1], acc);
                acc = mfma16(a0l, bh[gate][0], acc);
                acc = mfma16(a1l, bh[gate][1], acc);
                acc = mfma16(a0h, bl[gate][0], acc);
                acc = mfma16(a1h, bl[gate][1], acc);
                g[gate] = acc;
            }
            #pragma unroll
            for (int r = 0; r < 4; ++r) {
                const float ig = fsig(g[0][r]);
                const float fg = fsig(g[1][r]);
                const float gg = ftanh(g[2][r]);
                const float og = fsig(g[3][r]);
                const float cc = fg * cst[r] + ig * gg;
                cst[r] = cc;
                const float hv = og * ftanh(cc);
                const int ro = (q * 4 + r) * HSTR + 2 * n + p;
                dhi[ro] = hi16(hv);
                dlo[ro] = hi16(lo_resid(hv));
            }
        }
    }

    // ---- MLP head on h2_{T-1} (slot (T_LEN-1)&1 = 1) ----
    __syncthreads();
    if (wid == 2 && lane < 16) {
        const int fs = (T_LEN - 1) & 1;
        float h2v[32];
        #pragma unroll
        for (int kk = 0; kk < 32; ++kk) {
            h2v[kk] = __uint_as_float(((unsigned)(unsigned short)sh2hi[fs][lane * HSTR + kk]) << 16)
                    + __uint_as_float(((unsigned)(unsigned short)sh2lo[fs][lane * HSTR + kk]) << 16);
        }
        float pacc = b2[0];
        #pragma unroll 1
        for (int jj = 0; jj < 16; ++jj) {
            float acc = b1[jj];
            #pragma unroll
            for (int kk = 0; kk < 32; ++kk) acc += W1[jj * 32 + kk] * h2v[kk];
            pacc += W2[jj] * fmaxf(acc, 0.f);
        }
        out[blockIdx.x * 16 + lane] = pacc;
    }
}

} // namespace

extern "C" void kernel_launch(void* const* d_in, const int* in_sizes, int n_in,
                              void* d_out, int out_size, void* d_ws, size_t ws_size,
                              hipStream_t stream) {
    const float* x    = (const float*)d_in[0];
    const float* Wih0 = (const float*)d_in[1];
    const float* Whh0 = (const float*)d_in[2];
    const float* bih0 = (const float*)d_in[3];
    const float* bhh0 = (const float*)d_in[4];
    const float* Wih1 = (const float*)d_in[5];
    const float* Whh1 = (const float*)d_in[6];
    const float* bih1 = (const float*)d_in[7];
    const float* bhh1 = (const float*)d_in[8];
    const float* W1   = (const float*)d_in[9];
    const float* b1   = (const float*)d_in[10];
    const float* W2   = (const float*)d_in[11];
    const float* b2   = (const float*)d_in[12];

    const int batch  = out_size;            // 4096
    const int blocks = batch / 16;          // 256 blocks x 4 waves

    hipLaunchKernelGGL(lstm2_pipe4_kernel, dim3(blocks), dim3(256), 0, stream,
                       x, Wih0, Whh0, bih0, bhh0, Wih1, Whh1, bih1, bhh1,
                       W1, b1, W2, b2, (float*)d_out);
}